// Round 14
// baseline (82.842 us; speedup 1.0000x reference)
//
#include <hip/hip_runtime.h>

#define N_NODES 40000
#define N_EDGES 640000
#define NFEAT   128
#define H1      128   // 2*NHID
#define H2      64    // NHID

#define NBUCK   625   // dst>>6 buckets of 64 nodes
#define BCAP    2048  // capacity per bucket (avg 1024)
#define EPB     4096  // edges per bin block
#define NBINB   157   // bin blocks
#define HPAD    68    // uints per htile row (272B: 16B-aligned, bank-friendly)

// ---- workspace layout (byte offsets) ----
#define OFF_SUP1   0UL          // 40000*128 bf16 = 10,240,000
#define OFF_SUP2   10240000UL   // 40000*64  bf16 =  5,120,000
#define OFF_BUCK   15360000UL   // 625*2048 uint2 = 10,240,000
#define OFF_GSRT   25600000UL   // 625*2048 u32 = 5,120,000 (node-sorted records)
#define OFF_GNFO   30720000UL   // 40000 u32 packed (off<<12|cnt) = 160,000
#define OFF_GCUR   30880256UL   // 626 u32 -> 2,560 (padded)
#define OFF_W1T    30882816UL   // 128*128 bf16 -> 32,768
#define OFF_W2T    30915584UL   // 64*128 bf16 -> 16,384
// total 30,931,968 bytes

typedef unsigned int uint;
typedef unsigned short ushort;
typedef __attribute__((ext_vector_type(8))) short bf16x8;
typedef __attribute__((ext_vector_type(4))) float f32x4;

__device__ __forceinline__ float bl(uint u) { union { uint i; float f; } c; c.i = u << 16; return c.f; }
__device__ __forceinline__ float bh(uint u) { union { uint i; float f; } c; c.i = u & 0xFFFF0000u; return c.f; }
__device__ __forceinline__ ushort f2b(float f) {
    union { float f; uint i; } c; c.f = f;
    uint u = c.i + 0x7FFFu + ((c.i >> 16) & 1u);
    return (ushort)(u >> 16);
}

// zero bucket cursors + W1 -> W1T [n][k] bf16 ; W2 -> W2T [n][k] bf16
__global__ void init_k(uint* __restrict__ gcur,
                       const float* __restrict__ W1, const float* __restrict__ W2,
                       ushort* __restrict__ W1T, ushort* __restrict__ W2T) {
    const int i = blockIdx.x * 256 + threadIdx.x;
    if (i < NBUCK + 1) gcur[i] = 0;
    if (i < 128 * 128) {
        const int c = i >> 7, k = i & 127;
        W1T[i] = f2b(W1[k * 128 + c]);
    }
    if (i < 64 * 128) {
        const int c = i >> 7, k = i & 127;
        W2T[i] = f2b(W2[k * 64 + c]);
    }
}

// fused: blocks [0,157) bin edges by dst>>6 (LDS-staged, coalesced appends);
// blocks [157,314) run gemm1 (sup1 = x @ W1, MFMA, 256 rows/block).
__global__ __launch_bounds__(1024) void bingemm_k(const int* __restrict__ edst,
                                                  const int* __restrict__ esrc,
                                                  const float* __restrict__ ew,
                                                  uint* __restrict__ gcur,
                                                  uint2* __restrict__ buckets,
                                                  const float* __restrict__ x,
                                                  const ushort* __restrict__ W1T,
                                                  ushort* __restrict__ sup1) {
    __shared__ uint2 stage[EPB];          // 32 KB (bin branch only)
    __shared__ uint cntL[NBUCK + 1];
    __shared__ uint offL[NBUCK + 1];
    __shared__ uint gbase[NBUCK + 1];
    __shared__ int wsum[16];
    const int t = threadIdx.x;
    const int lane = t & 63, wv = t >> 6;

    if (blockIdx.x >= NBINB) {
        // ---- gemm1 branch: 16 waves x 16 rows = 256 rows/block ----
        const int gid = blockIdx.x - NBINB;
        const int m0 = gid * 256 + wv * 16;
        if (m0 >= N_NODES) return;
        const int r = lane & 15, kg = lane >> 4;

        bf16x8 a[4];
        const float* xp = x + (size_t)(m0 + r) * 128 + kg * 8;
#pragma unroll
        for (int kt = 0; kt < 4; ++kt) {
            float xf[8];
            *(float4*)(xf)     = *(const float4*)(xp + kt * 32);
            *(float4*)(xf + 4) = *(const float4*)(xp + kt * 32 + 4);
            bf16x8 v;
#pragma unroll
            for (int i = 0; i < 8; ++i) v[i] = (short)f2b(xf[i]);
            a[kt] = v;
        }
#pragma unroll
        for (int nt = 0; nt < 8; ++nt) {
            const ushort* wp = W1T + (size_t)(nt * 16 + r) * 128 + kg * 8;
            f32x4 acc = {0.f, 0.f, 0.f, 0.f};
#pragma unroll
            for (int kt = 0; kt < 4; ++kt) {
                const bf16x8 bfr = *(const bf16x8*)(wp + kt * 32);
                acc = __builtin_amdgcn_mfma_f32_16x16x32_bf16(a[kt], bfr, acc, 0, 0, 0);
            }
#pragma unroll
            for (int q = 0; q < 4; ++q)
                sup1[(size_t)(m0 + kg * 4 + q) * 128 + nt * 16 + r] = f2b(acc[q]);
        }
        return;
    }

    // ---- bin branch ----
    if (t < NBUCK + 1) cntL[t] = 0;
    __syncthreads();

    uint d_[4], rec_[4], rk_[4]; int b_[4];
#pragma unroll
    for (int k = 0; k < 4; ++k) {
        const int i = blockIdx.x * EPB + k * 1024 + t;
        uint d = 40000, rec = 0;          // sentinel -> overflow bucket 625
        if (i < N_EDGES) {
            d = (uint)edst[i];
            rec = ((uint)esrc[i] << 16) | (uint)f2b(ew[i]);
        }
        d_[k] = d; rec_[k] = rec; b_[k] = d >> 6;
        rk_[k] = atomicAdd(&cntL[b_[k]], 1u);
    }
    __syncthreads();

    {
        const int v = (t < NBUCK + 1) ? (int)cntL[t] : 0;
        int incl = v;
#pragma unroll
        for (int d = 1; d < 64; d <<= 1) {
            int o = __shfl_up(incl, d);
            if (lane >= d) incl += o;
        }
        if (lane == 63) wsum[wv] = incl;
        __syncthreads();
        if (t < 16) {
            int s = wsum[t];
#pragma unroll
            for (int d = 1; d < 16; d <<= 1) {
                int o = __shfl_up(s, d);
                if (t >= d) s += o;
            }
            wsum[t] = s;
        }
        __syncthreads();
        if (t < NBUCK + 1) {
            offL[t] = (uint)((wv ? wsum[wv - 1] : 0) + incl - v);
            gbase[t] = atomicAdd(&gcur[t], (uint)v);
        }
    }
    __syncthreads();

#pragma unroll
    for (int k = 0; k < 4; ++k) {
        uint2 s; s.x = d_[k]; s.y = rec_[k];
        stage[offL[b_[k]] + rk_[k]] = s;
    }
    __syncthreads();

#pragma unroll
    for (int k = 0; k < 4; ++k) {
        const int p = k * 1024 + t;
        const uint2 s = stage[p];
        const uint b = s.x >> 6;
        if (b < NBUCK) {
            const uint pos = gbase[b] + ((uint)p - offL[b]);
            if (pos < BCAP) buckets[(size_t)b * BCAP + pos] = s;
        }
    }
}

// fused layer-1 aggregate + gemm2: block = bucket (64 nodes).
// A: in-LDS counting sort by node (persisted to gsrt/gnfo for spmm2);
// B: QUARTER-WAVE per node — lanes split 4x16, quarter q owns node wv*4+q,
//    16 lanes x uint4 = full 128-feat row, 8-deep gather batches ->
//    4 independent chains x 8 = 32 loads in flight per wave;
// C: 16 waves MFMA htile @ W2 -> sup2 (no global h round-trip).
__global__ __launch_bounds__(1024) void spmmg_k(const ushort* __restrict__ sup,
                                                const uint* __restrict__ gcur,
                                                const uint2* __restrict__ buckets,
                                                const float* __restrict__ b1,
                                                const ushort* __restrict__ W2T,
                                                ushort* __restrict__ sup2,
                                                uint* __restrict__ gsrt,
                                                uint* __restrict__ gnfo) {
    __shared__ uint srt[BCAP];            // 8 KB
    __shared__ uint htile[64 * HPAD];     // 17.4 KB, bf16x2 per uint
    __shared__ uint cntL[64];
    __shared__ uint offL[64];
    const int t = threadIdx.x;
    const int bkt = blockIdx.x;
    if (t < 64) cntL[t] = 0;
    __syncthreads();

    const int cnt = min((int)gcur[bkt], BCAP);
    const uint* bp32 = (const uint*)(buckets + (size_t)bkt * BCAP);

    // A1: read edges (nt streaming loads on 32-bit halves), rank within node
    int n0 = -1, n1 = -1; uint rec0 = 0, rec1 = 0, rk0 = 0, rk1 = 0;
    if (t < cnt) {
        const uint dx = __builtin_nontemporal_load(&bp32[2 * t]);
        rec0 = __builtin_nontemporal_load(&bp32[2 * t + 1]);
        n0 = dx & 63; rk0 = atomicAdd(&cntL[n0], 1u);
    }
    if (t + 1024 < cnt) {
        const uint dx = __builtin_nontemporal_load(&bp32[2 * (t + 1024)]);
        rec1 = __builtin_nontemporal_load(&bp32[2 * (t + 1024) + 1]);
        n1 = dx & 63; rk1 = atomicAdd(&cntL[n1], 1u);
    }
    __syncthreads();

    // A2: wave 0 exclusive-scans the 64 counts
    if (t < 64) {
        const int v = (int)cntL[t];
        int incl = v;
#pragma unroll
        for (int d = 1; d < 64; d <<= 1) {
            int o = __shfl_up(incl, d);
            if (t >= d) incl += o;
        }
        offL[t] = (uint)(incl - v);
    }
    __syncthreads();

    // A3: place sorted
    if (n0 >= 0) srt[offL[n0] + rk0] = rec0;
    if (n1 >= 0) srt[offL[n1] + rk1] = rec1;
    __syncthreads();

    // persist sort for spmm2 (coalesced; overlaps phase B)
    if (t < cnt)        gsrt[(size_t)bkt * BCAP + t]        = srt[t];
    if (t + 1024 < cnt) gsrt[(size_t)bkt * BCAP + t + 1024] = srt[t + 1024];
    if (t < 64) gnfo[bkt * 64 + t] = (offL[t] << 12) | cntL[t];

    // B: quarter-wave per node
    const int lane = t & 63, wv = t >> 6;
    const int q = lane >> 4, ql = lane & 15;
    const uint4* sup128 = (const uint4*)sup;   // row = 16 uint4 (128 feats)
    {
        const int n = wv * 4 + q;
        const int e0 = (int)offL[n], c = (int)cntL[n];
        float acc[8] = {};
        int e = 0;
        for (; e + 8 <= c; e += 8) {
            uint r[8]; uint4 v[8];
#pragma unroll
            for (int k = 0; k < 8; ++k) r[k] = srt[e0 + e + k];
#pragma unroll
            for (int k = 0; k < 8; ++k) v[k] = sup128[((size_t)(r[k] >> 16) << 4) + ql];
#pragma unroll
            for (int k = 0; k < 8; ++k) {
                const float w = bl(r[k]);
                acc[0] = fmaf(w, bl(v[k].x), acc[0]); acc[1] = fmaf(w, bh(v[k].x), acc[1]);
                acc[2] = fmaf(w, bl(v[k].y), acc[2]); acc[3] = fmaf(w, bh(v[k].y), acc[3]);
                acc[4] = fmaf(w, bl(v[k].z), acc[4]); acc[5] = fmaf(w, bh(v[k].z), acc[5]);
                acc[6] = fmaf(w, bl(v[k].w), acc[6]); acc[7] = fmaf(w, bh(v[k].w), acc[7]);
            }
        }
        for (; e + 4 <= c; e += 4) {
            uint r[4]; uint4 v[4];
#pragma unroll
            for (int k = 0; k < 4; ++k) r[k] = srt[e0 + e + k];
#pragma unroll
            for (int k = 0; k < 4; ++k) v[k] = sup128[((size_t)(r[k] >> 16) << 4) + ql];
#pragma unroll
            for (int k = 0; k < 4; ++k) {
                const float w = bl(r[k]);
                acc[0] = fmaf(w, bl(v[k].x), acc[0]); acc[1] = fmaf(w, bh(v[k].x), acc[1]);
                acc[2] = fmaf(w, bl(v[k].y), acc[2]); acc[3] = fmaf(w, bh(v[k].y), acc[3]);
                acc[4] = fmaf(w, bl(v[k].z), acc[4]); acc[5] = fmaf(w, bh(v[k].z), acc[5]);
                acc[6] = fmaf(w, bl(v[k].w), acc[6]); acc[7] = fmaf(w, bh(v[k].w), acc[7]);
            }
        }
        for (; e < c; ++e) {
            const uint r0 = srt[e0 + e];
            const uint4 v0 = sup128[((size_t)(r0 >> 16) << 4) + ql];
            const float w = bl(r0);
            acc[0] = fmaf(w, bl(v0.x), acc[0]); acc[1] = fmaf(w, bh(v0.x), acc[1]);
            acc[2] = fmaf(w, bl(v0.y), acc[2]); acc[3] = fmaf(w, bh(v0.y), acc[3]);
            acc[4] = fmaf(w, bl(v0.z), acc[4]); acc[5] = fmaf(w, bh(v0.z), acc[5]);
            acc[6] = fmaf(w, bl(v0.w), acc[6]); acc[7] = fmaf(w, bh(v0.w), acc[7]);
        }
        // bias + relu + pack feats 8ql..8ql+7 -> one uint4 LDS store
        const float2 bq0 = ((const float2*)b1)[ql * 4 + 0];
        const float2 bq1 = ((const float2*)b1)[ql * 4 + 1];
        const float2 bq2 = ((const float2*)b1)[ql * 4 + 2];
        const float2 bq3 = ((const float2*)b1)[ql * 4 + 3];
        uint4 pk;
        pk.x = (uint)f2b(fmaxf(acc[0] + bq0.x, 0.f)) | ((uint)f2b(fmaxf(acc[1] + bq0.y, 0.f)) << 16);
        pk.y = (uint)f2b(fmaxf(acc[2] + bq1.x, 0.f)) | ((uint)f2b(fmaxf(acc[3] + bq1.y, 0.f)) << 16);
        pk.z = (uint)f2b(fmaxf(acc[4] + bq2.x, 0.f)) | ((uint)f2b(fmaxf(acc[5] + bq2.y, 0.f)) << 16);
        pk.w = (uint)f2b(fmaxf(acc[6] + bq3.x, 0.f)) | ((uint)f2b(fmaxf(acc[7] + bq3.y, 0.f)) << 16);
        *(uint4*)(htile + n * HPAD + ql * 4) = pk;
    }
    __syncthreads();

    // C: gemm2 on the tile. wave wv -> rowtile=wv>>2, ntile=wv&3.
    {
        const int r = lane & 15, kg = lane >> 4;
        const int rowtile = wv >> 2, ntile = wv & 3;
        const uint* hrow = htile + (rowtile * 16 + r) * HPAD + kg * 4;
        bf16x8 a[4];
#pragma unroll
        for (int kt = 0; kt < 4; ++kt) a[kt] = *(const bf16x8*)(hrow + kt * 16);

        const ushort* wp = W2T + (size_t)(ntile * 16 + r) * 128 + kg * 8;
        f32x4 acc = {0.f, 0.f, 0.f, 0.f};
#pragma unroll
        for (int kt = 0; kt < 4; ++kt) {
            const bf16x8 bfr = *(const bf16x8*)(wp + kt * 32);
            acc = __builtin_amdgcn_mfma_f32_16x16x32_bf16(a[kt], bfr, acc, 0, 0, 0);
        }
#pragma unroll
        for (int p = 0; p < 4; ++p)
            sup2[(size_t)(bkt * 64 + rowtile * 16 + kg * 4 + p) * 64 + ntile * 16 + r] = f2b(acc[p]);
    }
}

// out = spmm(adj, sup2) + b2.  Quarter-wave per node (uint2/lane, 8-deep).
__global__ __launch_bounds__(1024) void spmm2_k(const ushort* __restrict__ sup,
                                                const uint* __restrict__ gcur,
                                                const uint* __restrict__ gsrt,
                                                const uint* __restrict__ gnfo,
                                                const float* __restrict__ b2,
                                                float* __restrict__ out) {
    __shared__ uint srt[BCAP];
    __shared__ uint cntL[64];
    __shared__ uint offL[64];
    const int t = threadIdx.x;
    const int bkt = blockIdx.x;
    const int cnt = min((int)gcur[bkt], BCAP);

    if (t < 64) {
        const uint p = gnfo[bkt * 64 + t];
        offL[t] = p >> 12;
        cntL[t] = p & 0xFFFu;
    }
    const uint* gs = gsrt + (size_t)bkt * BCAP;
    if (t < cnt)        srt[t]        = gs[t];
    if (t + 1024 < cnt) srt[t + 1024] = gs[t + 1024];
    __syncthreads();

    const int lane = t & 63, wv = t >> 6;
    const int q = lane >> 4, ql = lane & 15;
    const uint2* sup64 = (const uint2*)sup;    // row = 16 uint2 (64 feats)
    const int n = wv * 4 + q;
    const int e0 = (int)offL[n], c = (int)cntL[n];
    float acc[4] = {};
    int e = 0;
    for (; e + 8 <= c; e += 8) {
        uint r[8]; uint2 v[8];
#pragma unroll
        for (int k = 0; k < 8; ++k) r[k] = srt[e0 + e + k];
#pragma unroll
        for (int k = 0; k < 8; ++k) v[k] = sup64[((size_t)(r[k] >> 16) << 4) + ql];
#pragma unroll
        for (int k = 0; k < 8; ++k) {
            const float w = bl(r[k]);
            acc[0] = fmaf(w, bl(v[k].x), acc[0]); acc[1] = fmaf(w, bh(v[k].x), acc[1]);
            acc[2] = fmaf(w, bl(v[k].y), acc[2]); acc[3] = fmaf(w, bh(v[k].y), acc[3]);
        }
    }
    for (; e + 4 <= c; e += 4) {
        uint r[4]; uint2 v[4];
#pragma unroll
        for (int k = 0; k < 4; ++k) r[k] = srt[e0 + e + k];
#pragma unroll
        for (int k = 0; k < 4; ++k) v[k] = sup64[((size_t)(r[k] >> 16) << 4) + ql];
#pragma unroll
        for (int k = 0; k < 4; ++k) {
            const float w = bl(r[k]);
            acc[0] = fmaf(w, bl(v[k].x), acc[0]); acc[1] = fmaf(w, bh(v[k].x), acc[1]);
            acc[2] = fmaf(w, bl(v[k].y), acc[2]); acc[3] = fmaf(w, bh(v[k].y), acc[3]);
        }
    }
    for (; e < c; ++e) {
        const uint r0 = srt[e0 + e];
        const uint2 v0 = sup64[((size_t)(r0 >> 16) << 4) + ql];
        const float w = bl(r0);
        acc[0] = fmaf(w, bl(v0.x), acc[0]); acc[1] = fmaf(w, bh(v0.x), acc[1]);
        acc[2] = fmaf(w, bl(v0.y), acc[2]); acc[3] = fmaf(w, bh(v0.y), acc[3]);
    }
    // bias + write feats 4ql..4ql+3 (float4, coalesced 256B/node)
    const float4 bb = ((const float4*)b2)[ql];
    f32x4 res = {acc[0] + bb.x, acc[1] + bb.y, acc[2] + bb.z, acc[3] + bb.w};
    __builtin_nontemporal_store(res, (f32x4*)out + (size_t)(bkt * 64 + n) * 16 + ql);
}

extern "C" void kernel_launch(void* const* d_in, const int* in_sizes, int n_in,
                              void* d_out, int out_size, void* d_ws, size_t ws_size,
                              hipStream_t stream) {
    const float* x    = (const float*)d_in[0];
    const int*   esrc = (const int*)d_in[1];
    const int*   edst = (const int*)d_in[2];
    const float* ew   = (const float*)d_in[3];
    const float* W1   = (const float*)d_in[4];
    const float* b1   = (const float*)d_in[5];
    const float* W2   = (const float*)d_in[6];
    const float* b2   = (const float*)d_in[7];
    float* out = (float*)d_out;

    char* ws = (char*)d_ws;
    ushort* sup1    = (ushort*)(ws + OFF_SUP1);
    ushort* sup2    = (ushort*)(ws + OFF_SUP2);
    uint2*  buckets = (uint2*)(ws + OFF_BUCK);
    uint*   gsrt    = (uint*)(ws + OFF_GSRT);
    uint*   gnfo    = (uint*)(ws + OFF_GNFO);
    uint*   gcur    = (uint*)(ws + OFF_GCUR);
    ushort* W1T     = (ushort*)(ws + OFF_W1T);
    ushort* W2T     = (ushort*)(ws + OFF_W2T);

    init_k<<<64, 256, 0, stream>>>(gcur, W1, W2, W1T, W2T);
    bingemm_k<<<NBINB + 157, 1024, 0, stream>>>(edst, esrc, ew, gcur, buckets, x, W1T, sup1);
    spmmg_k<<<NBUCK, 1024, 0, stream>>>(sup1, gcur, buckets, b1, W2T, sup2, gsrt, gnfo);
    spmm2_k<<<NBUCK, 1024, 0, stream>>>(sup2, gcur, gsrt, gnfo, b2, out);
}

// Round 15
// 71.929 us; speedup vs baseline: 1.1517x; 1.1517x over previous
//
#include <hip/hip_runtime.h>

#define N_NODES 40000
#define N_EDGES 640000
#define NFEAT   128
#define H1      128   // 2*NHID
#define H2      64    // NHID

#define NBUCK   625   // dst>>6 buckets of 64 nodes
#define BCAP    2048  // capacity per bucket (avg 1024)
#define EPB     4096  // edges per bin block
#define NBINB   157   // bin blocks
#define HPAD    68    // uints per htile row (272B: 16B-aligned, bank-friendly)
#define WPAD    136   // ushorts per W-tile row (272B)

// ---- workspace layout (byte offsets) ----
#define OFF_SUP1   0UL          // 40000*128 bf16 = 10,240,000
#define OFF_SUP2   10240000UL   // 40000*64  bf16 =  5,120,000
#define OFF_BUCK   15360000UL   // 625*2048 uint2 = 10,240,000
#define OFF_GCUR   25600000UL   // 626 u32 -> 2,560 (padded)
// total 25,602,560 bytes

typedef unsigned int uint;
typedef unsigned short ushort;
typedef __attribute__((ext_vector_type(8))) short bf16x8;
typedef __attribute__((ext_vector_type(4))) float f32x4;
typedef __attribute__((ext_vector_type(2))) float f32x2;

__device__ __forceinline__ float bl(uint u) { union { uint i; float f; } c; c.i = u << 16; return c.f; }
__device__ __forceinline__ float bh(uint u) { union { uint i; float f; } c; c.i = u & 0xFFFF0000u; return c.f; }
__device__ __forceinline__ ushort f2b(float f) {
    union { float f; uint i; } c; c.f = f;
    uint u = c.i + 0x7FFFu + ((c.i >> 16) & 1u);
    return (ushort)(u >> 16);
}

// zero bucket cursors (1 block)
__global__ void init_k(uint* __restrict__ gcur) {
    if (threadIdx.x < NBUCK + 1) gcur[threadIdx.x] = 0;
}

// fused: blocks [0,157) bin edges by dst>>6 (LDS-staged, coalesced appends);
// blocks [157,314) run gemm1 (sup1 = x @ W1, MFMA, W1 self-transposed to LDS).
__global__ __launch_bounds__(1024) void bingemm_k(const int* __restrict__ edst,
                                                  const int* __restrict__ esrc,
                                                  const float* __restrict__ ew,
                                                  uint* __restrict__ gcur,
                                                  uint2* __restrict__ buckets,
                                                  const float* __restrict__ x,
                                                  const float* __restrict__ W1,
                                                  ushort* __restrict__ sup1) {
    __shared__ uint2 stage[EPB];          // 32 KB (bin branch)
    __shared__ ushort wlds[128 * WPAD];   // 34.8 KB (gemm branch W1T [n][k])
    __shared__ uint cntL[NBUCK + 1];
    __shared__ uint offL[NBUCK + 1];
    __shared__ uint gbase[NBUCK + 1];
    __shared__ int wsum[16];
    const int t = threadIdx.x;
    const int lane = t & 63, wv = t >> 6;

    if (blockIdx.x >= NBINB) {
        // ---- gemm1 branch: 16 waves x 16 rows = 256 rows/block ----
        const int gid = blockIdx.x - NBINB;
        const int m0 = gid * 256 + wv * 16;
        // W1 [k][n] f32 -> wlds [n][k] bf16 (coalesced reads, one-time LDS scatter)
        for (int i = t; i < 128 * 128; i += 1024) {
            const int k = i >> 7, n = i & 127;
            wlds[n * WPAD + k] = f2b(W1[i]);
        }
        __syncthreads();
        if (m0 >= N_NODES) return;
        const int r = lane & 15, kg = lane >> 4;

        bf16x8 a[4];
        const float* xp = x + (size_t)(m0 + r) * 128 + kg * 8;
#pragma unroll
        for (int kt = 0; kt < 4; ++kt) {
            float xf[8];
            *(float4*)(xf)     = *(const float4*)(xp + kt * 32);
            *(float4*)(xf + 4) = *(const float4*)(xp + kt * 32 + 4);
            bf16x8 v;
#pragma unroll
            for (int i = 0; i < 8; ++i) v[i] = (short)f2b(xf[i]);
            a[kt] = v;
        }
#pragma unroll
        for (int nt = 0; nt < 8; ++nt) {
            const ushort* wp = wlds + (nt * 16 + r) * WPAD + kg * 8;
            f32x4 acc = {0.f, 0.f, 0.f, 0.f};
#pragma unroll
            for (int kt = 0; kt < 4; ++kt) {
                const bf16x8 bfr = *(const bf16x8*)(wp + kt * 32);
                acc = __builtin_amdgcn_mfma_f32_16x16x32_bf16(a[kt], bfr, acc, 0, 0, 0);
            }
#pragma unroll
            for (int q = 0; q < 4; ++q)
                sup1[(size_t)(m0 + kg * 4 + q) * 128 + nt * 16 + r] = f2b(acc[q]);
        }
        return;
    }

    // ---- bin branch ----
    if (t < NBUCK + 1) cntL[t] = 0;
    __syncthreads();

    uint d_[4], rec_[4], rk_[4]; int b_[4];
#pragma unroll
    for (int k = 0; k < 4; ++k) {
        const int i = blockIdx.x * EPB + k * 1024 + t;
        uint d = 40000, rec = 0;          // sentinel -> overflow bucket 625
        if (i < N_EDGES) {
            d = (uint)edst[i];
            rec = ((uint)esrc[i] << 16) | (uint)f2b(ew[i]);
        }
        d_[k] = d; rec_[k] = rec; b_[k] = d >> 6;
        rk_[k] = atomicAdd(&cntL[b_[k]], 1u);
    }
    __syncthreads();

    {
        const int v = (t < NBUCK + 1) ? (int)cntL[t] : 0;
        int incl = v;
#pragma unroll
        for (int d = 1; d < 64; d <<= 1) {
            int o = __shfl_up(incl, d);
            if (lane >= d) incl += o;
        }
        if (lane == 63) wsum[wv] = incl;
        __syncthreads();
        if (t < 16) {
            int s = wsum[t];
#pragma unroll
            for (int d = 1; d < 16; d <<= 1) {
                int o = __shfl_up(s, d);
                if (t >= d) s += o;
            }
            wsum[t] = s;
        }
        __syncthreads();
        if (t < NBUCK + 1) {
            offL[t] = (uint)((wv ? wsum[wv - 1] : 0) + incl - v);
            gbase[t] = atomicAdd(&gcur[t], (uint)v);
        }
    }
    __syncthreads();

#pragma unroll
    for (int k = 0; k < 4; ++k) {
        uint2 s; s.x = d_[k]; s.y = rec_[k];
        stage[offL[b_[k]] + rk_[k]] = s;
    }
    __syncthreads();

#pragma unroll
    for (int k = 0; k < 4; ++k) {
        const int p = k * 1024 + t;
        const uint2 s = stage[p];
        const uint b = s.x >> 6;
        if (b < NBUCK) {
            const uint pos = gbase[b] + ((uint)p - offL[b]);
            if (pos < BCAP) buckets[(size_t)b * BCAP + pos] = s;
        }
    }
}

// fused layer-1 aggregate + gemm2: block = bucket (64 nodes).
// A: in-LDS counting sort by node; B: wave-per-node register aggregation
// (8 gathers in flight) -> relu(agg+b1) -> LDS htile; C: 16 waves MFMA
// htile @ W2 (W2 self-transposed to LDS) -> sup2.
__global__ __launch_bounds__(1024) void spmmg_k(const ushort* __restrict__ sup,
                                                const uint* __restrict__ gcur,
                                                const uint2* __restrict__ buckets,
                                                const float* __restrict__ b1,
                                                const float* __restrict__ W2,
                                                ushort* __restrict__ sup2) {
    __shared__ uint srt[BCAP];            // 8 KB
    __shared__ uint htile[64 * HPAD];     // 17.4 KB
    __shared__ ushort w2t[64 * WPAD];     // 17.4 KB, W2T [n][k]
    __shared__ uint cntL[64];
    __shared__ uint offL[64];
    const int t = threadIdx.x;
    const int bkt = blockIdx.x;
    if (t < 64) cntL[t] = 0;
    // W2 [k][64] f32 -> w2t [n][k] bf16 (coalesced reads)
    for (int i = t; i < 128 * 64; i += 1024) {
        const int k = i >> 6, n = i & 63;
        w2t[n * WPAD + k] = f2b(W2[i]);
    }
    __syncthreads();

    const int cnt = min((int)gcur[bkt], BCAP);
    const uint* bp32 = (const uint*)(buckets + (size_t)bkt * BCAP);

    // A1: read edges (nt streaming loads), rank within node
    int n0 = -1, n1 = -1; uint rec0 = 0, rec1 = 0, rk0 = 0, rk1 = 0;
    if (t < cnt) {
        const uint dx = __builtin_nontemporal_load(&bp32[2 * t]);
        rec0 = __builtin_nontemporal_load(&bp32[2 * t + 1]);
        n0 = dx & 63; rk0 = atomicAdd(&cntL[n0], 1u);
    }
    if (t + 1024 < cnt) {
        const uint dx = __builtin_nontemporal_load(&bp32[2 * (t + 1024)]);
        rec1 = __builtin_nontemporal_load(&bp32[2 * (t + 1024) + 1]);
        n1 = dx & 63; rk1 = atomicAdd(&cntL[n1], 1u);
    }
    __syncthreads();

    // A2: wave 0 exclusive-scans the 64 counts
    if (t < 64) {
        const int v = (int)cntL[t];
        int incl = v;
#pragma unroll
        for (int d = 1; d < 64; d <<= 1) {
            int o = __shfl_up(incl, d);
            if (t >= d) incl += o;
        }
        offL[t] = (uint)(incl - v);
    }
    __syncthreads();

    // A3: place sorted
    if (n0 >= 0) srt[offL[n0] + rk0] = rec0;
    if (n1 >= 0) srt[offL[n1] + rk1] = rec1;
    __syncthreads();

    // B: wave wv aggregates nodes wv*4..wv*4+3 into htile
    const int lane = t & 63, wv = t >> 6;
    const uint* sup32 = (const uint*)sup;
    const float2 bb = ((const float2*)b1)[lane];
#pragma unroll
    for (int j = 0; j < 4; ++j) {
        const int n = wv * 4 + j;
        const int e0 = (int)offL[n], c = (int)cntL[n];
        float a0 = 0.f, a1 = 0.f, a2 = 0.f, a3 = 0.f;
        int e = 0;
        for (; e + 8 <= c; e += 8) {
            uint r[8], v[8];
#pragma unroll
            for (int k = 0; k < 8; ++k) r[k] = srt[e0 + e + k];
#pragma unroll
            for (int k = 0; k < 8; ++k) v[k] = sup32[((size_t)(r[k] >> 16) << 6) + lane];
#pragma unroll
            for (int k = 0; k < 8; k += 2) {
                const float w0 = bl(r[k]), w1 = bl(r[k + 1]);
                a0 = fmaf(w0, bl(v[k]), a0);     a1 = fmaf(w0, bh(v[k]), a1);
                a2 = fmaf(w1, bl(v[k + 1]), a2); a3 = fmaf(w1, bh(v[k + 1]), a3);
            }
        }
        for (; e + 4 <= c; e += 4) {
            uint r[4], v[4];
#pragma unroll
            for (int k = 0; k < 4; ++k) r[k] = srt[e0 + e + k];
#pragma unroll
            for (int k = 0; k < 4; ++k) v[k] = sup32[((size_t)(r[k] >> 16) << 6) + lane];
#pragma unroll
            for (int k = 0; k < 4; k += 2) {
                const float w0 = bl(r[k]), w1 = bl(r[k + 1]);
                a0 = fmaf(w0, bl(v[k]), a0);     a1 = fmaf(w0, bh(v[k]), a1);
                a2 = fmaf(w1, bl(v[k + 1]), a2); a3 = fmaf(w1, bh(v[k + 1]), a3);
            }
        }
        for (; e < c; ++e) {
            const uint r0 = srt[e0 + e];
            const uint v0 = sup32[((size_t)(r0 >> 16) << 6) + lane];
            a0 = fmaf(bl(r0), bl(v0), a0); a1 = fmaf(bl(r0), bh(v0), a1);
        }
        const float f0 = fmaxf((a0 + a2) + bb.x, 0.f);
        const float f1 = fmaxf((a1 + a3) + bb.y, 0.f);
        htile[n * HPAD + lane] = (uint)f2b(f0) | ((uint)f2b(f1) << 16);
    }
    __syncthreads();

    // C: gemm2 on the tile. wave wv -> rowtile=wv>>2, ntile=wv&3.
    {
        const int r = lane & 15, kg = lane >> 4;
        const int rowtile = wv >> 2, ntile = wv & 3;
        const uint* hrow = htile + (rowtile * 16 + r) * HPAD + kg * 4;
        bf16x8 a[4];
#pragma unroll
        for (int kt = 0; kt < 4; ++kt) a[kt] = *(const bf16x8*)(hrow + kt * 16);

        const ushort* wp = w2t + (ntile * 16 + r) * WPAD + kg * 8;
        f32x4 acc = {0.f, 0.f, 0.f, 0.f};
#pragma unroll
        for (int kt = 0; kt < 4; ++kt) {
            const bf16x8 bfr = *(const bf16x8*)(wp + kt * 32);
            acc = __builtin_amdgcn_mfma_f32_16x16x32_bf16(a[kt], bfr, acc, 0, 0, 0);
        }
#pragma unroll
        for (int q = 0; q < 4; ++q)
            sup2[(size_t)(bkt * 64 + rowtile * 16 + kg * 4 + q) * 64 + ntile * 16 + r] = f2b(acc[q]);
    }
}

// out = spmm(adj, sup2) + b2.  Block = bucket; in-LDS sort; full-wave per node.
__global__ __launch_bounds__(1024) void spmm2_k(const ushort* __restrict__ sup,
                                                const uint* __restrict__ gcur,
                                                const uint2* __restrict__ buckets,
                                                const float* __restrict__ b2,
                                                float* __restrict__ out) {
    __shared__ uint srt[BCAP];
    __shared__ uint cntL[64];
    __shared__ uint offL[64];
    const int t = threadIdx.x;
    const int bkt = blockIdx.x;
    if (t < 64) cntL[t] = 0;
    __syncthreads();

    const int cnt = min((int)gcur[bkt], BCAP);
    const uint* bp32 = (const uint*)(buckets + (size_t)bkt * BCAP);

    int n0 = -1, n1 = -1; uint rec0 = 0, rec1 = 0, rk0 = 0, rk1 = 0;
    if (t < cnt) {
        const uint dx = __builtin_nontemporal_load(&bp32[2 * t]);
        rec0 = __builtin_nontemporal_load(&bp32[2 * t + 1]);
        n0 = dx & 63; rk0 = atomicAdd(&cntL[n0], 1u);
    }
    if (t + 1024 < cnt) {
        const uint dx = __builtin_nontemporal_load(&bp32[2 * (t + 1024)]);
        rec1 = __builtin_nontemporal_load(&bp32[2 * (t + 1024) + 1]);
        n1 = dx & 63; rk1 = atomicAdd(&cntL[n1], 1u);
    }
    __syncthreads();

    if (t < 64) {
        const int v = (int)cntL[t];
        int incl = v;
#pragma unroll
        for (int d = 1; d < 64; d <<= 1) {
            int o = __shfl_up(incl, d);
            if (t >= d) incl += o;
        }
        offL[t] = (uint)(incl - v);
    }
    __syncthreads();

    if (n0 >= 0) srt[offL[n0] + rk0] = rec0;
    if (n1 >= 0) srt[offL[n1] + rk1] = rec1;
    __syncthreads();

    const int lane = t & 63, wv = t >> 6;
    const int hh = lane >> 5, l32 = lane & 31;
    const uint* sup32 = (const uint*)sup;
    const float2 bb = ((const float2*)b2)[l32];
#pragma unroll
    for (int j = 0; j < 4; ++j) {
        const int n = wv * 4 + j;
        const int e0 = (int)offL[n], c = (int)cntL[n];
        float d0 = 0.f, d1 = 0.f, d2 = 0.f, d3 = 0.f;
        int e = 0;
        for (; e + 8 <= c; e += 8) {
            const uint r0 = srt[e0 + e + hh],     r1 = srt[e0 + e + 2 + hh];
            const uint r2 = srt[e0 + e + 4 + hh], r3 = srt[e0 + e + 6 + hh];
            const uint v0 = sup32[((size_t)(r0 >> 16) << 5) + l32];
            const uint v1 = sup32[((size_t)(r1 >> 16) << 5) + l32];
            const uint v2 = sup32[((size_t)(r2 >> 16) << 5) + l32];
            const uint v3 = sup32[((size_t)(r3 >> 16) << 5) + l32];
            d0 = fmaf(bl(r0), bl(v0), d0); d1 = fmaf(bl(r0), bh(v0), d1);
            d2 = fmaf(bl(r1), bl(v1), d2); d3 = fmaf(bl(r1), bh(v1), d3);
            d0 = fmaf(bl(r2), bl(v2), d0); d1 = fmaf(bl(r2), bh(v2), d1);
            d2 = fmaf(bl(r3), bl(v3), d2); d3 = fmaf(bl(r3), bh(v3), d3);
        }
        for (; e + 2 <= c; e += 2) {
            const uint r0 = srt[e0 + e + hh];
            const uint v0 = sup32[((size_t)(r0 >> 16) << 5) + l32];
            d0 = fmaf(bl(r0), bl(v0), d0); d1 = fmaf(bl(r0), bh(v0), d1);
        }
        if (e < c && hh == 0) {
            const uint r0 = srt[e0 + e];
            const uint v0 = sup32[((size_t)(r0 >> 16) << 5) + l32];
            d0 = fmaf(bl(r0), bl(v0), d0); d1 = fmaf(bl(r0), bh(v0), d1);
        }
        float g0 = d0 + d2, g1 = d1 + d3;
        g0 += __shfl_xor(g0, 32); g1 += __shfl_xor(g1, 32);
        if (hh == 0) {
            f32x2 res = {g0 + bb.x, g1 + bb.y};
            __builtin_nontemporal_store(res, (f32x2*)out + (size_t)(bkt * 64 + n) * 32 + l32);
        }
    }
}

extern "C" void kernel_launch(void* const* d_in, const int* in_sizes, int n_in,
                              void* d_out, int out_size, void* d_ws, size_t ws_size,
                              hipStream_t stream) {
    const float* x    = (const float*)d_in[0];
    const int*   esrc = (const int*)d_in[1];
    const int*   edst = (const int*)d_in[2];
    const float* ew   = (const float*)d_in[3];
    const float* W1   = (const float*)d_in[4];
    const float* b1   = (const float*)d_in[5];
    const float* W2   = (const float*)d_in[6];
    const float* b2   = (const float*)d_in[7];
    float* out = (float*)d_out;

    char* ws = (char*)d_ws;
    ushort* sup1    = (ushort*)(ws + OFF_SUP1);
    ushort* sup2    = (ushort*)(ws + OFF_SUP2);
    uint2*  buckets = (uint2*)(ws + OFF_BUCK);
    uint*   gcur    = (uint*)(ws + OFF_GCUR);

    init_k<<<1, 1024, 0, stream>>>(gcur);
    bingemm_k<<<NBINB + 157, 1024, 0, stream>>>(edst, esrc, ew, gcur, buckets, x, W1, sup1);
    spmmg_k<<<NBUCK, 1024, 0, stream>>>(sup1, gcur, buckets, b1, W2, sup2);
    spmm2_k<<<NBUCK, 1024, 0, stream>>>(sup2, gcur, buckets, b2, out);
}

// Round 17
// 71.298 us; speedup vs baseline: 1.1619x; 1.0089x over previous
//
#include <hip/hip_runtime.h>

#define N_NODES 40000
#define N_EDGES 640000
#define NFEAT   128
#define H1      128   // 2*NHID
#define H2      64    // NHID

#define NBUCK   625   // dst>>6 buckets of 64 nodes
#define BCAP    2048  // capacity per bucket (avg 1024)
#define EPB     4096  // edges per bin block
#define NBINB   157   // bin blocks
#define HPAD    68    // uints per htile row (272B: 16B-aligned, bank-friendly)
#define WPAD    136   // ushorts per W-tile row (272B)

// ---- workspace layout (byte offsets) ----
#define OFF_SUP1   0UL          // 40000*128 bf16 = 10,240,000
#define OFF_SUP2   10240000UL   // 40000*64  bf16 =  5,120,000
#define OFF_BUCK   15360000UL   // 625*2048 uint2 = 10,240,000
#define OFF_GCUR   25600000UL   // 626 u32 -> 2,560 (padded)
// total 25,602,560 bytes

typedef unsigned int uint;
typedef unsigned short ushort;
typedef __attribute__((ext_vector_type(8))) short bf16x8;
typedef __attribute__((ext_vector_type(4))) float f32x4;
typedef __attribute__((ext_vector_type(2))) float f32x2;

__device__ __forceinline__ float bl(uint u) { union { uint i; float f; } c; c.i = u << 16; return c.f; }
__device__ __forceinline__ float bh(uint u) { union { uint i; float f; } c; c.i = u & 0xFFFF0000u; return c.f; }
__device__ __forceinline__ ushort f2b(float f) {
    union { float f; uint i; } c; c.f = f;
    uint u = c.i + 0x7FFFu + ((c.i >> 16) & 1u);
    return (ushort)(u >> 16);
}

// zero bucket cursors (1 block)
__global__ void init_k(uint* __restrict__ gcur) {
    if (threadIdx.x < NBUCK + 1) gcur[threadIdx.x] = 0;
}

// fused: blocks [0,157) bin edges by dst>>6 (LDS-staged, coalesced appends);
// blocks [157,314) run gemm1 (sup1 = x @ W1, MFMA, W1 self-transposed to LDS).
__global__ __launch_bounds__(1024) void bingemm_k(const int* __restrict__ edst,
                                                  const int* __restrict__ esrc,
                                                  const float* __restrict__ ew,
                                                  uint* __restrict__ gcur,
                                                  uint2* __restrict__ buckets,
                                                  const float* __restrict__ x,
                                                  const float* __restrict__ W1,
                                                  ushort* __restrict__ sup1) {
    __shared__ uint2 stage[EPB];          // 32 KB (bin branch)
    __shared__ ushort wlds[128 * WPAD];   // 34.8 KB (gemm branch W1T [n][k])
    __shared__ uint cntL[NBUCK + 1];
    __shared__ uint offL[NBUCK + 1];
    __shared__ uint gbase[NBUCK + 1];
    __shared__ int wsum[16];
    const int t = threadIdx.x;
    const int lane = t & 63, wv = t >> 6;

    if (blockIdx.x >= NBINB) {
        // ---- gemm1 branch: 16 waves x 16 rows = 256 rows/block ----
        const int gid = blockIdx.x - NBINB;
        const int m0 = gid * 256 + wv * 16;
        // W1 [k][n] f32 -> wlds [n][k] bf16 (coalesced reads, one-time LDS scatter)
        for (int i = t; i < 128 * 128; i += 1024) {
            const int k = i >> 7, n = i & 127;
            wlds[n * WPAD + k] = f2b(W1[i]);
        }
        __syncthreads();
        if (m0 >= N_NODES) return;
        const int r = lane & 15, kg = lane >> 4;

        bf16x8 a[4];
        const float* xp = x + (size_t)(m0 + r) * 128 + kg * 8;
#pragma unroll
        for (int kt = 0; kt < 4; ++kt) {
            float xf[8];
            *(float4*)(xf)     = *(const float4*)(xp + kt * 32);
            *(float4*)(xf + 4) = *(const float4*)(xp + kt * 32 + 4);
            bf16x8 v;
#pragma unroll
            for (int i = 0; i < 8; ++i) v[i] = (short)f2b(xf[i]);
            a[kt] = v;
        }
#pragma unroll
        for (int nt = 0; nt < 8; ++nt) {
            const ushort* wp = wlds + (nt * 16 + r) * WPAD + kg * 8;
            f32x4 acc = {0.f, 0.f, 0.f, 0.f};
#pragma unroll
            for (int kt = 0; kt < 4; ++kt) {
                const bf16x8 bfr = *(const bf16x8*)(wp + kt * 32);
                acc = __builtin_amdgcn_mfma_f32_16x16x32_bf16(a[kt], bfr, acc, 0, 0, 0);
            }
#pragma unroll
            for (int q = 0; q < 4; ++q)
                sup1[(size_t)(m0 + kg * 4 + q) * 128 + nt * 16 + r] = f2b(acc[q]);
        }
        return;
    }

    // ---- bin branch ----
    if (t < NBUCK + 1) cntL[t] = 0;
    __syncthreads();

    uint d_[4], rec_[4], rk_[4]; int b_[4];
#pragma unroll
    for (int k = 0; k < 4; ++k) {
        const int i = blockIdx.x * EPB + k * 1024 + t;
        uint d = 40000, rec = 0;          // sentinel -> overflow bucket 625
        if (i < N_EDGES) {
            d = (uint)edst[i];
            rec = ((uint)esrc[i] << 16) | (uint)f2b(ew[i]);
        }
        d_[k] = d; rec_[k] = rec; b_[k] = d >> 6;
        rk_[k] = atomicAdd(&cntL[b_[k]], 1u);
    }
    __syncthreads();

    {
        const int v = (t < NBUCK + 1) ? (int)cntL[t] : 0;
        int incl = v;
#pragma unroll
        for (int d = 1; d < 64; d <<= 1) {
            int o = __shfl_up(incl, d);
            if (lane >= d) incl += o;
        }
        if (lane == 63) wsum[wv] = incl;
        __syncthreads();
        if (t < 16) {
            int s = wsum[t];
#pragma unroll
            for (int d = 1; d < 16; d <<= 1) {
                int o = __shfl_up(s, d);
                if (t >= d) s += o;
            }
            wsum[t] = s;
        }
        __syncthreads();
        if (t < NBUCK + 1) {
            offL[t] = (uint)((wv ? wsum[wv - 1] : 0) + incl - v);
            gbase[t] = atomicAdd(&gcur[t], (uint)v);
        }
    }
    __syncthreads();

#pragma unroll
    for (int k = 0; k < 4; ++k) {
        uint2 s; s.x = d_[k]; s.y = rec_[k];
        stage[offL[b_[k]] + rk_[k]] = s;
    }
    __syncthreads();

#pragma unroll
    for (int k = 0; k < 4; ++k) {
        const int p = k * 1024 + t;
        const uint2 s = stage[p];
        const uint b = s.x >> 6;
        if (b < NBUCK) {
            const uint pos = gbase[b] + ((uint)p - offL[b]);
            if (pos < BCAP) buckets[(size_t)b * BCAP + pos] = s;
        }
    }
}

// fused layer-1 aggregate + gemm2: block = bucket (64 nodes).
// A: in-LDS counting sort by node; B: wave-per-node register aggregation
// (8 gathers in flight) -> relu(agg+b1) -> LDS htile; C: 16 waves MFMA
// htile @ W2 (W2 self-transposed to LDS) -> sup2.
__global__ __launch_bounds__(1024) void spmmg_k(const ushort* __restrict__ sup,
                                                const uint* __restrict__ gcur,
                                                const uint2* __restrict__ buckets,
                                                const float* __restrict__ b1,
                                                const float* __restrict__ W2,
                                                ushort* __restrict__ sup2) {
    __shared__ uint srt[BCAP];            // 8 KB
    __shared__ uint htile[64 * HPAD];     // 17.4 KB
    __shared__ ushort w2t[64 * WPAD];     // 17.4 KB, W2T [n][k]
    __shared__ uint cntL[64];
    __shared__ uint offL[64];
    const int t = threadIdx.x;
    const int bkt = blockIdx.x;
    if (t < 64) cntL[t] = 0;
    // W2 [k][64] f32 -> w2t [n][k] bf16 (coalesced reads)
    for (int i = t; i < 128 * 64; i += 1024) {
        const int k = i >> 6, n = i & 63;
        w2t[n * WPAD + k] = f2b(W2[i]);
    }
    __syncthreads();

    const int cnt = min((int)gcur[bkt], BCAP);
    const uint* bp32 = (const uint*)(buckets + (size_t)bkt * BCAP);

    // A1: read edges (nt streaming loads), rank within node
    int n0 = -1, n1 = -1; uint rec0 = 0, rec1 = 0, rk0 = 0, rk1 = 0;
    if (t < cnt) {
        const uint dx = __builtin_nontemporal_load(&bp32[2 * t]);
        rec0 = __builtin_nontemporal_load(&bp32[2 * t + 1]);
        n0 = dx & 63; rk0 = atomicAdd(&cntL[n0], 1u);
    }
    if (t + 1024 < cnt) {
        const uint dx = __builtin_nontemporal_load(&bp32[2 * (t + 1024)]);
        rec1 = __builtin_nontemporal_load(&bp32[2 * (t + 1024) + 1]);
        n1 = dx & 63; rk1 = atomicAdd(&cntL[n1], 1u);
    }
    __syncthreads();

    // A2: wave 0 exclusive-scans the 64 counts
    if (t < 64) {
        const int v = (int)cntL[t];
        int incl = v;
#pragma unroll
        for (int d = 1; d < 64; d <<= 1) {
            int o = __shfl_up(incl, d);
            if (t >= d) incl += o;
        }
        offL[t] = (uint)(incl - v);
    }
    __syncthreads();

    // A3: place sorted
    if (n0 >= 0) srt[offL[n0] + rk0] = rec0;
    if (n1 >= 0) srt[offL[n1] + rk1] = rec1;
    __syncthreads();

    // B: wave wv aggregates nodes wv*4..wv*4+3 into htile
    const int lane = t & 63, wv = t >> 6;
    const uint* sup32 = (const uint*)sup;
    const float2 bb = ((const float2*)b1)[lane];
#pragma unroll
    for (int j = 0; j < 4; ++j) {
        const int n = wv * 4 + j;
        const int e0 = (int)offL[n], c = (int)cntL[n];
        float a0 = 0.f, a1 = 0.f, a2 = 0.f, a3 = 0.f;
        int e = 0;
        for (; e + 8 <= c; e += 8) {
            uint r[8], v[8];
#pragma unroll
            for (int k = 0; k < 8; ++k) r[k] = srt[e0 + e + k];
#pragma unroll
            for (int k = 0; k < 8; ++k) v[k] = sup32[((size_t)(r[k] >> 16) << 6) + lane];
#pragma unroll
            for (int k = 0; k < 8; k += 2) {
                const float w0 = bl(r[k]), w1 = bl(r[k + 1]);
                a0 = fmaf(w0, bl(v[k]), a0);     a1 = fmaf(w0, bh(v[k]), a1);
                a2 = fmaf(w1, bl(v[k + 1]), a2); a3 = fmaf(w1, bh(v[k + 1]), a3);
            }
        }
        for (; e + 4 <= c; e += 4) {
            uint r[4], v[4];
#pragma unroll
            for (int k = 0; k < 4; ++k) r[k] = srt[e0 + e + k];
#pragma unroll
            for (int k = 0; k < 4; ++k) v[k] = sup32[((size_t)(r[k] >> 16) << 6) + lane];
#pragma unroll
            for (int k = 0; k < 4; k += 2) {
                const float w0 = bl(r[k]), w1 = bl(r[k + 1]);
                a0 = fmaf(w0, bl(v[k]), a0);     a1 = fmaf(w0, bh(v[k]), a1);
                a2 = fmaf(w1, bl(v[k + 1]), a2); a3 = fmaf(w1, bh(v[k + 1]), a3);
            }
        }
        for (; e < c; ++e) {
            const uint r0 = srt[e0 + e];
            const uint v0 = sup32[((size_t)(r0 >> 16) << 6) + lane];
            a0 = fmaf(bl(r0), bl(v0), a0); a1 = fmaf(bl(r0), bh(v0), a1);
        }
        const float f0 = fmaxf((a0 + a2) + bb.x, 0.f);
        const float f1 = fmaxf((a1 + a3) + bb.y, 0.f);
        htile[n * HPAD + lane] = (uint)f2b(f0) | ((uint)f2b(f1) << 16);
    }
    __syncthreads();

    // C: gemm2 on the tile. wave wv -> rowtile=wv>>2, ntile=wv&3.
    {
        const int r = lane & 15, kg = lane >> 4;
        const int rowtile = wv >> 2, ntile = wv & 3;
        const uint* hrow = htile + (rowtile * 16 + r) * HPAD + kg * 4;
        bf16x8 a[4];
#pragma unroll
        for (int kt = 0; kt < 4; ++kt) a[kt] = *(const bf16x8*)(hrow + kt * 16);

        const ushort* wp = w2t + (ntile * 16 + r) * WPAD + kg * 8;
        f32x4 acc = {0.f, 0.f, 0.f, 0.f};
#pragma unroll
        for (int kt = 0; kt < 4; ++kt) {
            const bf16x8 bfr = *(const bf16x8*)(wp + kt * 32);
            acc = __builtin_amdgcn_mfma_f32_16x16x32_bf16(a[kt], bfr, acc, 0, 0, 0);
        }
#pragma unroll
        for (int q = 0; q < 4; ++q)
            sup2[(size_t)(bkt * 64 + rowtile * 16 + kg * 4 + q) * 64 + ntile * 16 + r] = f2b(acc[q]);
    }
}

// out = spmm(adj, sup2) + b2.  Block = bucket; in-LDS sort; full-wave per node.
__global__ __launch_bounds__(1024) void spmm2_k(const ushort* __restrict__ sup,
                                                const uint* __restrict__ gcur,
                                                const uint2* __restrict__ buckets,
                                                const float* __restrict__ b2,
                                                float* __restrict__ out) {
    __shared__ uint srt[BCAP];
    __shared__ uint cntL[64];
    __shared__ uint offL[64];
    const int t = threadIdx.x;
    const int bkt = blockIdx.x;
    if (t < 64) cntL[t] = 0;
    __syncthreads();

    const int cnt = min((int)gcur[bkt], BCAP);
    const uint* bp32 = (const uint*)(buckets + (size_t)bkt * BCAP);

    int n0 = -1, n1 = -1; uint rec0 = 0, rec1 = 0, rk0 = 0, rk1 = 0;
    if (t < cnt) {
        const uint dx = __builtin_nontemporal_load(&bp32[2 * t]);
        rec0 = __builtin_nontemporal_load(&bp32[2 * t + 1]);
        n0 = dx & 63; rk0 = atomicAdd(&cntL[n0], 1u);
    }
    if (t + 1024 < cnt) {
        const uint dx = __builtin_nontemporal_load(&bp32[2 * (t + 1024)]);
        rec1 = __builtin_nontemporal_load(&bp32[2 * (t + 1024) + 1]);
        n1 = dx & 63; rk1 = atomicAdd(&cntL[n1], 1u);
    }
    __syncthreads();

    if (t < 64) {
        const int v = (int)cntL[t];
        int incl = v;
#pragma unroll
        for (int d = 1; d < 64; d <<= 1) {
            int o = __shfl_up(incl, d);
            if (t >= d) incl += o;
        }
        offL[t] = (uint)(incl - v);
    }
    __syncthreads();

    if (n0 >= 0) srt[offL[n0] + rk0] = rec0;
    if (n1 >= 0) srt[offL[n1] + rk1] = rec1;
    __syncthreads();

    const int lane = t & 63, wv = t >> 6;
    const int hh = lane >> 5, l32 = lane & 31;
    const uint* sup32 = (const uint*)sup;
    const float2 bb = ((const float2*)b2)[l32];
#pragma unroll
    for (int j = 0; j < 4; ++j) {
        const int n = wv * 4 + j;
        const int e0 = (int)offL[n], c = (int)cntL[n];
        float d0 = 0.f, d1 = 0.f, d2 = 0.f, d3 = 0.f;
        int e = 0;
        for (; e + 8 <= c; e += 8) {
            const uint r0 = srt[e0 + e + hh],     r1 = srt[e0 + e + 2 + hh];
            const uint r2 = srt[e0 + e + 4 + hh], r3 = srt[e0 + e + 6 + hh];
            const uint v0 = sup32[((size_t)(r0 >> 16) << 5) + l32];
            const uint v1 = sup32[((size_t)(r1 >> 16) << 5) + l32];
            const uint v2 = sup32[((size_t)(r2 >> 16) << 5) + l32];
            const uint v3 = sup32[((size_t)(r3 >> 16) << 5) + l32];
            d0 = fmaf(bl(r0), bl(v0), d0); d1 = fmaf(bl(r0), bh(v0), d1);
            d2 = fmaf(bl(r1), bl(v1), d2); d3 = fmaf(bl(r1), bh(v1), d3);
            d0 = fmaf(bl(r2), bl(v2), d0); d1 = fmaf(bl(r2), bh(v2), d1);
            d2 = fmaf(bl(r3), bl(v3), d2); d3 = fmaf(bl(r3), bh(v3), d3);
        }
        for (; e + 2 <= c; e += 2) {
            const uint r0 = srt[e0 + e + hh];
            const uint v0 = sup32[((size_t)(r0 >> 16) << 5) + l32];
            d0 = fmaf(bl(r0), bl(v0), d0); d1 = fmaf(bl(r0), bh(v0), d1);
        }
        if (e < c && hh == 0) {
            const uint r0 = srt[e0 + e];
            const uint v0 = sup32[((size_t)(r0 >> 16) << 5) + l32];
            d0 = fmaf(bl(r0), bl(v0), d0); d1 = fmaf(bl(r0), bh(v0), d1);
        }
        float g0 = d0 + d2, g1 = d1 + d3;
        g0 += __shfl_xor(g0, 32); g1 += __shfl_xor(g1, 32);
        if (hh == 0) {
            f32x2 res = {g0 + bb.x, g1 + bb.y};
            __builtin_nontemporal_store(res, (f32x2*)out + (size_t)(bkt * 64 + n) * 32 + l32);
        }
    }
}

extern "C" void kernel_launch(void* const* d_in, const int* in_sizes, int n_in,
                              void* d_out, int out_size, void* d_ws, size_t ws_size,
                              hipStream_t stream) {
    const float* x    = (const float*)d_in[0];
    const int*   esrc = (const int*)d_in[1];
    const int*   edst = (const int*)d_in[2];
    const float* ew   = (const float*)d_in[3];
    const float* W1   = (const float*)d_in[4];
    const float* b1   = (const float*)d_in[5];
    const float* W2   = (const float*)d_in[6];
    const float* b2   = (const float*)d_in[7];
    float* out = (float*)d_out;

    char* ws = (char*)d_ws;
    ushort* sup1    = (ushort*)(ws + OFF_SUP1);
    ushort* sup2    = (ushort*)(ws + OFF_SUP2);
    uint2*  buckets = (uint2*)(ws + OFF_BUCK);
    uint*   gcur    = (uint*)(ws + OFF_GCUR);

    init_k<<<1, 1024, 0, stream>>>(gcur);
    bingemm_k<<<NBINB + 157, 1024, 0, stream>>>(edst, esrc, ew, gcur, buckets, x, W1, sup1);
    spmmg_k<<<NBUCK, 1024, 0, stream>>>(sup1, gcur, buckets, b1, W2, sup2);
    spmm2_k<<<NBUCK, 1024, 0, stream>>>(sup2, gcur, buckets, b2, out);
}